// Round 1
// baseline (2117.434 us; speedup 1.0000x reference)
//
#include <hip/hip_runtime.h>
#include <hip/hip_bf16.h>
#include <math.h>

typedef unsigned short u16;
typedef __attribute__((ext_vector_type(4))) float floatx4;
typedef __attribute__((ext_vector_type(8))) short shortx8;

#define NB 64
#define NNODE 512
#define NTOT (NB*NNODE)      // 32768
#define DDIM 128
#define DEG 16
#define NEDGE (NTOT*DEG)     // 524288
#define HFF 512
#define EPSV 1e-5f

__device__ __forceinline__ float bf2f(u16 u){
  union { unsigned int i; float f; } v; v.i = ((unsigned int)u) << 16; return v.f;
}
__device__ __forceinline__ u16 f2bf(float f){
  union { float f; unsigned int i; } v; v.f = f;
  unsigned int r = v.i + 0x7FFFu + ((v.i >> 16) & 1u);
  return (u16)(r >> 16);
}
__device__ __forceinline__ float gelu_f(float x){
  return 0.5f * x * (1.0f + erff(x * 0.70710678118654752f));
}

// ---------------- CSR build (dst-sorted) ----------------
__global__ void zero_kernel(int* p, int n){
  int i = blockIdx.x*256 + threadIdx.x; if (i < n) p[i] = 0;
}
__global__ void hist_kernel(const int* __restrict__ dst, int* __restrict__ counts){
  int e = blockIdx.x*256 + threadIdx.x; atomicAdd(&counts[dst[e]], 1);
}
__global__ void scan_kernel(const int* counts, int* row_ptr, int* cursor){
  __shared__ int part[1024];
  int t = threadIdx.x; int base = t*32;
  int loc[32]; int s = 0;
  #pragma unroll
  for (int i = 0; i < 32; ++i){ loc[i] = counts[base+i]; s += loc[i]; }
  part[t] = s; __syncthreads();
  for (int off = 1; off < 1024; off <<= 1){
    int v = (t >= off) ? part[t-off] : 0;
    __syncthreads(); part[t] += v; __syncthreads();
  }
  int run = part[t] - s;  // exclusive prefix of this chunk
  #pragma unroll
  for (int i = 0; i < 32; ++i){ row_ptr[base+i] = run; cursor[base+i] = run; run += loc[i]; }
  if (t == 0) row_ptr[NTOT] = part[1023];
}
__global__ void scatter_kernel(const int* __restrict__ src, const int* __restrict__ dst,
                               int* __restrict__ cursor, int* __restrict__ ssrc, int* __restrict__ seid){
  int e = blockIdx.x*256 + threadIdx.x;
  int d = dst[e];
  int pos = atomicAdd(&cursor[d], 1);
  ssrc[pos] = src[e]; seid[pos] = e;
}

// ---------------- generic bf16 MFMA GEMM: C[M x (128*gridY)] = A[MxK] @ B ----------------
struct GemmCfg {
  const float* B[4];
  const float* bias[4];
  float* o32[4];
  u16* o16[4];
  int ldb, ld_out, K, bcolmul, ocolmul, gelu;
};

template<bool ABF>
__global__ __launch_bounds__(256, 2)
void gemm_kernel(const void* __restrict__ Aptr, const int* __restrict__ a_idx, GemmCfg cfg){
  __shared__ u16 As[128][136];   // +8 pad: breaks bank conflicts, keeps 16B alignment (272B rows)
  __shared__ u16 Bs[128][136];   // stored transposed: Bs[n][k]
  const int t = threadIdx.x;
  const int wave = t >> 6, lane = t & 63, quad = lane >> 4, l16 = lane & 15;
  const int row0 = blockIdx.x * 128;
  const int cb = blockIdx.y;
  const float* Bp = cfg.B[cb];
  const int col0b = cb * cfg.bcolmul;
  const int K = cfg.K;
  floatx4 acc[2][8] = {};
  for (int kc = 0; kc < K; kc += 128){
    if (!ABF){
      const float* Af = (const float*)Aptr;
      #pragma unroll
      for (int j = 0; j < 16; ++j){
        int idx4 = t + j*256;
        int elem = idx4 << 2;
        int r = elem >> 7, c = elem & 127;
        int row = row0 + r; int arow = a_idx ? a_idx[row] : row;
        float4 f = *(const float4*)(Af + (size_t)arow*K + kc + c);
        u16* wp = &As[r][c];
        wp[0]=f2bf(f.x); wp[1]=f2bf(f.y); wp[2]=f2bf(f.z); wp[3]=f2bf(f.w);
      }
    } else {
      const u16* Ab = (const u16*)Aptr;
      #pragma unroll
      for (int j = 0; j < 8; ++j){
        int idx8 = t + j*256;
        int elem = idx8 << 3;
        int r = elem >> 7, c = elem & 127;
        int row = row0 + r; int arow = a_idx ? a_idx[row] : row;
        uint4 d = *(const uint4*)(Ab + (size_t)arow*K + kc + c);
        *(uint4*)&As[r][c] = d;
      }
    }
    // stage B transposed: each thread grabs 4 k-rows of one column
    #pragma unroll
    for (int j = 0; j < 16; ++j){
      int gi = t + j*256;
      int c = gi & 127;
      int k4 = (gi >> 7) << 2;
      size_t boff = (size_t)(kc + k4)*cfg.ldb + col0b + c;
      float f0 = Bp[boff];
      float f1 = Bp[boff + cfg.ldb];
      float f2 = Bp[boff + 2*(size_t)cfg.ldb];
      float f3 = Bp[boff + 3*(size_t)cfg.ldb];
      u16* wp = &Bs[c][k4];
      wp[0]=f2bf(f0); wp[1]=f2bf(f1); wp[2]=f2bf(f2); wp[3]=f2bf(f3);
    }
    __syncthreads();
    const int wm0 = wave*32;
    #pragma unroll
    for (int kk = 0; kk < 4; ++kk){
      shortx8 a0 = *(const shortx8*)&As[wm0 + l16][kk*32 + quad*8];
      shortx8 a1 = *(const shortx8*)&As[wm0 + 16 + l16][kk*32 + quad*8];
      #pragma unroll
      for (int nt = 0; nt < 8; ++nt){
        shortx8 bfr = *(const shortx8*)&Bs[nt*16 + l16][kk*32 + quad*8];
        acc[0][nt] = __builtin_amdgcn_mfma_f32_16x16x32_bf16(a0, bfr, acc[0][nt], 0, 0, 0);
        acc[1][nt] = __builtin_amdgcn_mfma_f32_16x16x32_bf16(a1, bfr, acc[1][nt], 0, 0, 0);
      }
    }
    __syncthreads();
  }
  const float* biasp = cfg.bias[cb];
  float* o32 = cfg.o32[cb];
  u16* o16 = cfg.o16[cb];
  const int col0o = cb * cfg.ocolmul;
  const int wm0 = wave*32;
  #pragma unroll
  for (int nt = 0; nt < 8; ++nt){
    int col = col0o + nt*16 + l16;
    float bvv = biasp ? biasp[col] : 0.0f;
    #pragma unroll
    for (int mt = 0; mt < 2; ++mt){
      #pragma unroll
      for (int r = 0; r < 4; ++r){
        int row = row0 + wm0 + mt*16 + quad*4 + r;
        float v = acc[mt][nt][r] + bvv;
        if (cfg.gelu) v = gelu_f(v);
        size_t off = (size_t)row * cfg.ld_out + col;
        if (o32) o32[off] = v;
        if (o16) o16[off] = f2bf(v);
      }
    }
  }
}

// ---------------- attention: one wave per dst node, online softmax ----------------
__global__ __launch_bounds__(256)
void attn_kernel(const int* __restrict__ row_ptr, const int* __restrict__ ssrc,
                 const u16* __restrict__ e_rows,
                 const u16* __restrict__ qb, const u16* __restrict__ kb, const u16* __restrict__ vb,
                 const float* __restrict__ skip, float* __restrict__ y){
  int b = blockIdx.x;
  int xcd = b & 7, i = b >> 3;                // XCD swizzle: whole graph on one XCD for k/v L2 locality
  int g = xcd*8 + (i >> 7), slot = i & 127;
  int wave = threadIdx.x >> 6, lane = threadIdx.x & 63;
  int dst = g*NNODE + slot*4 + wave;
  const int ch = lane*2;                      // 2 channels per lane; head h = lanes 8h..8h+7
  ushort2 qp = *(const ushort2*)(qb + (size_t)dst*DDIM + ch);
  float q0 = bf2f(qp.x), q1 = bf2f(qp.y);
  int beg = row_ptr[dst], end = row_ptr[dst+1];
  float mh = -INFINITY, lh = 0.f, a0 = 0.f, a1 = 0.f;
  for (int idx = beg; idx < end; ++idx){
    int s = ssrc[idx];
    ushort2 ep = *(const ushort2*)(e_rows + (size_t)idx*DDIM + ch);
    ushort2 kp = *(const ushort2*)(kb + (size_t)s*DDIM + ch);
    ushort2 vp = *(const ushort2*)(vb + (size_t)s*DDIM + ch);
    float e0 = bf2f(ep.x), e1 = bf2f(ep.y);
    float p = q0*(bf2f(kp.x)+e0) + q1*(bf2f(kp.y)+e1);
    p += __shfl_xor(p, 1);
    p += __shfl_xor(p, 2);
    p += __shfl_xor(p, 4);                    // per-head dot over dh=16 (8 lanes x 2ch)
    float sc = p * 0.25f;                     // 1/sqrt(16)
    float mn = fmaxf(mh, sc);
    float cs = __expf(mh - mn), w = __expf(sc - mn);
    lh = lh*cs + w;
    a0 = a0*cs + w*(bf2f(vp.x)+e0);
    a1 = a1*cs + w*(bf2f(vp.y)+e1);
    mh = mn;
  }
  float r = lh > 0.f ? 1.0f/lh : 0.f;
  float2 sp = *(const float2*)(skip + (size_t)dst*DDIM + ch);
  float2 o; o.x = a0*r + sp.x; o.y = a1*r + sp.y;
  *(float2*)(y + (size_t)dst*DDIM + ch) = o;
}

// ---------------- GraphNorm (D=128 path) ----------------
__global__ __launch_bounds__(256)
void gstats_kernel(const float* __restrict__ y, const float* __restrict__ alpha,
                   float* __restrict__ meanb, float* __restrict__ invb){
  __shared__ float ls[256], lq[256];
  int g = blockIdx.x, t = threadIdx.x;
  int c = t & 127, half = t >> 7;
  const float* base = y + (size_t)g*NNODE*DDIM;
  float s = 0.f, q = 0.f;
  for (int i = half; i < NNODE; i += 2){
    float v = gelu_f(base[(size_t)i*DDIM + c]);
    s += v; q += v*v;
  }
  ls[t] = s; lq[t] = q; __syncthreads();
  if (half == 0){
    s += ls[t+128]; q += lq[t+128];
    float mean = s * (1.f/NNODE);
    float msq  = q * (1.f/NNODE);
    float a = alpha[c];
    float var = msq - mean*mean*a*(2.f - a);
    meanb[g*DDIM + c] = mean;
    invb[g*DDIM + c]  = rsqrtf(var + EPSV);
  }
}
__global__ void gnorm_kernel(const float* __restrict__ y, const float* __restrict__ meanb,
                             const float* __restrict__ invb, const float* __restrict__ gamma,
                             const float* __restrict__ beta, const float* __restrict__ alpha,
                             float* __restrict__ xout){
  int gid = blockIdx.x*256 + threadIdx.x;
  int c = gid & 127, node = gid >> 7, g = node >> 9;
  float v = gelu_f(y[gid]);
  xout[gid] = gamma[c]*(v - alpha[c]*meanb[g*DDIM+c])*invb[g*DDIM+c] + beta[c];
}

// ---------------- GraphNorm (Hff=512 path, bf16 data) ----------------
__global__ __launch_bounds__(512)
void fstats_kernel(const u16* __restrict__ gb, const float* __restrict__ alpha,
                   float* __restrict__ meanb, float* __restrict__ invb){
  int g = blockIdx.x, c = threadIdx.x;
  const u16* base = gb + (size_t)g*NNODE*HFF;
  float s = 0.f, q = 0.f;
  for (int i = 0; i < NNODE; ++i){
    float v = bf2f(base[(size_t)i*HFF + c]);
    s += v; q += v*v;
  }
  float mean = s * (1.f/NNODE);
  float msq  = q * (1.f/NNODE);
  float a = alpha[c];
  meanb[g*HFF + c] = mean;
  invb[g*HFF + c]  = rsqrtf(msq - mean*mean*a*(2.f-a) + EPSV);
}
__global__ void fnorm_kernel(const u16* __restrict__ gb, const float* __restrict__ meanb,
                             const float* __restrict__ invb, const float* __restrict__ gamma,
                             const float* __restrict__ beta, const float* __restrict__ alpha,
                             u16* __restrict__ hn){
  int gid = blockIdx.x*256 + threadIdx.x;
  int c = gid & (HFF-1); int node = gid >> 9; int g = node >> 9;
  float v = bf2f(gb[gid]);
  hn[gid] = f2bf(gamma[c]*(v - alpha[c]*meanb[g*HFF+c])*invb[g*HFF+c] + beta[c]);
}

// ---------------- mean pool ----------------
__global__ __launch_bounds__(128)
void pool_kernel(const float* __restrict__ xo, float* __restrict__ gf){
  int g = blockIdx.x, c = threadIdx.x;
  const float* base = xo + (size_t)g*NNODE*DDIM;
  float s = 0.f;
  for (int i = 0; i < NNODE; ++i) s += base[(size_t)i*DDIM + c];
  gf[g*DDIM + c] = s * (1.f/NNODE);
}

extern "C" void kernel_launch(void* const* d_in, const int* in_sizes, int n_in,
                              void* d_out, int out_size, void* d_ws, size_t ws_size,
                              hipStream_t stream){
  const float* x_in = (const float*)d_in[0];
  const int*   eidx = (const int*)d_in[1];
  const float* ea   = (const float*)d_in[2];
  const float* Wq   = (const float*)d_in[4];
  const float* bq   = (const float*)d_in[5];
  const float* Wk   = (const float*)d_in[6];
  const float* bk   = (const float*)d_in[7];
  const float* Wv   = (const float*)d_in[8];
  const float* bv   = (const float*)d_in[9];
  const float* We   = (const float*)d_in[10];
  const float* Wsk  = (const float*)d_in[11];
  const float* bsk  = (const float*)d_in[12];
  const float* gn_g = (const float*)d_in[13];
  const float* gn_b = (const float*)d_in[14];
  const float* gn_a = (const float*)d_in[15];
  const float* ffW1 = (const float*)d_in[16];
  const float* ffb1 = (const float*)d_in[17];
  const float* fgn_g= (const float*)d_in[18];
  const float* fgn_b= (const float*)d_in[19];
  const float* fgn_a= (const float*)d_in[20];
  const float* ffW2 = (const float*)d_in[21];
  const float* ffb2 = (const float*)d_in[22];
  const int* srcA = eidx;
  const int* dstA = eidx + NEDGE;

  char* w = (char*)d_ws;
  auto alloc = [&](size_t bytes)->char*{ char* p = w; w += (bytes + 255) & ~(size_t)255; return p; };
  int* counts  = (int*)alloc((size_t)NTOT*4);
  int* row_ptr = (int*)alloc((size_t)(NTOT+1)*4);
  int* ssrc    = (int*)alloc((size_t)NEDGE*4);
  int* seid    = (int*)alloc((size_t)NEDGE*4);
  u16* e_bf    = (u16*)alloc((size_t)NEDGE*DDIM*2);   // 128 MiB; reused as g/hn in FFN phase
  u16* qb      = (u16*)alloc((size_t)NTOT*DDIM*2);
  u16* kb      = (u16*)alloc((size_t)NTOT*DDIM*2);
  u16* vb      = (u16*)alloc((size_t)NTOT*DDIM*2);
  float* skipb = (float*)alloc((size_t)NTOT*DDIM*4);
  float* yb    = (float*)alloc((size_t)NTOT*DDIM*4);
  float* xcur  = (float*)alloc((size_t)NTOT*DDIM*4);
  float* meanb = (float*)alloc((size_t)NB*HFF*4);
  float* invb  = (float*)alloc((size_t)NB*HFF*4);
  u16* g_bf  = e_bf;                                  // alias (e dead by FFN phase)
  u16* hn_bf = e_bf + (size_t)NTOT*HFF;

  // CSR build (same every call)
  zero_kernel<<<NTOT/256, 256, 0, stream>>>(counts, NTOT);
  hist_kernel<<<NEDGE/256, 256, 0, stream>>>(dstA, counts);
  scan_kernel<<<1, 1024, 0, stream>>>(counts, row_ptr, counts);
  scatter_kernel<<<NEDGE/256, 256, 0, stream>>>(srcA, dstA, counts, ssrc, seid);

  const float* x_l = x_in;
  for (int l = 0; l < 3; ++l){
    // e = edge_attr[sorted] @ We[l]  -> bf16, in dst-sorted order
    GemmCfg ce = {};
    for (int i2 = 0; i2 < 4; ++i2){ ce.B[i2] = We + (size_t)l*DDIM*DDIM; ce.o16[i2] = e_bf; }
    ce.ldb = DDIM; ce.ld_out = DDIM; ce.K = DDIM; ce.bcolmul = 0; ce.ocolmul = 0; ce.gelu = 0;
    gemm_kernel<false><<<dim3(NEDGE/128, 1), 256, 0, stream>>>(ea, seid, ce);

    // q,k,v (bf16) + skip (fp32) fused: grid.y picks the weight
    GemmCfg cq = {};
    cq.B[0]=Wq + (size_t)l*DDIM*DDIM; cq.B[1]=Wk + (size_t)l*DDIM*DDIM;
    cq.B[2]=Wv + (size_t)l*DDIM*DDIM; cq.B[3]=Wsk + (size_t)l*DDIM*DDIM;
    cq.bias[0]=bq + l*DDIM; cq.bias[1]=bk + l*DDIM; cq.bias[2]=bv + l*DDIM; cq.bias[3]=bsk + l*DDIM;
    cq.o16[0]=qb; cq.o16[1]=kb; cq.o16[2]=vb; cq.o16[3]=nullptr;
    cq.o32[3]=skipb;
    cq.ldb = DDIM; cq.ld_out = DDIM; cq.K = DDIM; cq.bcolmul = 0; cq.ocolmul = 0; cq.gelu = 0;
    gemm_kernel<false><<<dim3(NTOT/128, 4), 256, 0, stream>>>(x_l, nullptr, cq);

    attn_kernel<<<NTOT/4, 256, 0, stream>>>(row_ptr, ssrc, e_bf, qb, kb, vb, skipb, yb);

    if (l < 2){
      gstats_kernel<<<NB, 256, 0, stream>>>(yb, gn_a + l*DDIM, meanb, invb);
      gnorm_kernel<<<NTOT*DDIM/256, 256, 0, stream>>>(yb, meanb, invb,
          gn_g + l*DDIM, gn_b + l*DDIM, gn_a + l*DDIM, xcur);
      x_l = xcur;
    }
  }

  // FFN: g = gelu(y @ ffW1 + ffb1)  (bf16, aliases e region)
  GemmCfg c1 = {};
  for (int i2 = 0; i2 < 4; ++i2){ c1.B[i2] = ffW1; c1.bias[i2] = ffb1; c1.o16[i2] = g_bf; }
  c1.ldb = HFF; c1.ld_out = HFF; c1.K = DDIM; c1.bcolmul = 128; c1.ocolmul = 128; c1.gelu = 1;
  gemm_kernel<false><<<dim3(NTOT/128, 4), 256, 0, stream>>>(yb, nullptr, c1);

  fstats_kernel<<<NB, 512, 0, stream>>>(g_bf, fgn_a, meanb, invb);
  fnorm_kernel<<<NTOT*HFF/256, 256, 0, stream>>>(g_bf, meanb, invb, fgn_g, fgn_b, fgn_a, hn_bf);

  // x_out = hn @ ffW2 + ffb2 -> d_out (node embeddings, fp32)
  GemmCfg c2 = {};
  for (int i2 = 0; i2 < 4; ++i2){ c2.B[i2] = ffW2; c2.bias[i2] = ffb2; c2.o32[i2] = (float*)d_out; }
  c2.ldb = DDIM; c2.ld_out = DDIM; c2.K = HFF; c2.bcolmul = 0; c2.ocolmul = 0; c2.gelu = 0;
  gemm_kernel<true><<<dim3(NTOT/128, 1), 256, 0, stream>>>(hn_bf, nullptr, c2);

  pool_kernel<<<NB, 128, 0, stream>>>((const float*)d_out, (float*)d_out + (size_t)NTOT*DDIM);
}

// Round 2
// 1810.701 us; speedup vs baseline: 1.1694x; 1.1694x over previous
//
#include <hip/hip_runtime.h>
#include <hip/hip_bf16.h>
#include <math.h>

typedef unsigned short u16;
typedef __attribute__((ext_vector_type(4))) float floatx4;
typedef __attribute__((ext_vector_type(8))) short shortx8;

#define NB 64
#define NNODE 512
#define NTOT (NB*NNODE)      // 32768
#define DDIM 128
#define DEG 16
#define NEDGE (NTOT*DEG)     // 524288
#define HFF 512
#define EPSV 1e-5f

__device__ __forceinline__ float bf2f(u16 u){
  union { unsigned int i; float f; } v; v.i = ((unsigned int)u) << 16; return v.f;
}
__device__ __forceinline__ u16 f2bf(float f){
  union { float f; unsigned int i; } v; v.f = f;
  unsigned int r = v.i + 0x7FFFu + ((v.i >> 16) & 1u);
  return (u16)(r >> 16);
}
__device__ __forceinline__ float gelu_f(float x){
  return 0.5f * x * (1.0f + erff(x * 0.70710678118654752f));
}

// ---------------- CSR build (dst-sorted) ----------------
__global__ void zero_kernel(int* p, int n){
  int i = blockIdx.x*256 + threadIdx.x; if (i < n) p[i] = 0;
}
__global__ void zerof_kernel(float* p, int n){
  int i = blockIdx.x*256 + threadIdx.x; if (i < n) p[i] = 0.f;
}
__global__ void hist_kernel(const int* __restrict__ dst, int* __restrict__ counts){
  int e = blockIdx.x*256 + threadIdx.x; atomicAdd(&counts[dst[e]], 1);
}
__global__ void scan_kernel(const int* counts, int* row_ptr, int* cursor){
  __shared__ int part[1024];
  int t = threadIdx.x; int base = t*32;
  int loc[32]; int s = 0;
  #pragma unroll
  for (int i = 0; i < 32; ++i){ loc[i] = counts[base+i]; s += loc[i]; }
  part[t] = s; __syncthreads();
  for (int off = 1; off < 1024; off <<= 1){
    int v = (t >= off) ? part[t-off] : 0;
    __syncthreads(); part[t] += v; __syncthreads();
  }
  int run = part[t] - s;  // exclusive prefix of this chunk
  #pragma unroll
  for (int i = 0; i < 32; ++i){ row_ptr[base+i] = run; cursor[base+i] = run; run += loc[i]; }
  if (t == 0) row_ptr[NTOT] = part[1023];
}
__global__ void scatter_kernel(const int* __restrict__ src, const int* __restrict__ dst,
                               int* __restrict__ cursor, int* __restrict__ ssrc, int* __restrict__ seid){
  int e = blockIdx.x*256 + threadIdx.x;
  int d = dst[e];
  int pos = atomicAdd(&cursor[d], 1);
  ssrc[pos] = src[e]; seid[pos] = e;
}

// ---------------- generic bf16 MFMA GEMM: C[M x (128*gridY)] = A[MxK] @ B ----------------
struct GemmCfg {
  const float* B[4];
  const float* bias[4];
  float* o32[4];
  u16* o16[4];
  u16* dumpA;       // if set (and !ABF): write staged bf16 A tile to dumpA (row-major, ld=K)
  float* pool;      // if set (with o32): atomic per-graph column mean into pool[g*128+col]
  int ldb, ld_out, K, bcolmul, ocolmul, gelu;
};

template<bool ABF>
__global__ __launch_bounds__(256, 2)
void gemm_kernel(const void* __restrict__ Aptr, const int* __restrict__ a_idx, GemmCfg cfg){
  __shared__ u16 As[128][136];   // +8 pad: breaks bank conflicts, keeps 16B alignment (272B rows)
  __shared__ u16 Bs[128][136];   // stored transposed: Bs[n][k]
  const int t = threadIdx.x;
  const int wave = t >> 6, lane = t & 63, quad = lane >> 4, l16 = lane & 15;
  const int row0 = blockIdx.x * 128;
  const int cb = blockIdx.y;
  const float* Bp = cfg.B[cb];
  const int col0b = cb * cfg.bcolmul;
  const int K = cfg.K;
  floatx4 acc[2][8] = {};
  for (int kc = 0; kc < K; kc += 128){
    if (!ABF){
      const float* Af = (const float*)Aptr;
      #pragma unroll
      for (int j = 0; j < 16; ++j){
        int idx4 = t + j*256;
        int elem = idx4 << 2;
        int r = elem >> 7, c = elem & 127;
        int row = row0 + r; int arow = a_idx ? a_idx[row] : row;
        float4 f = *(const float4*)(Af + (size_t)arow*K + kc + c);
        u16* wp = &As[r][c];
        wp[0]=f2bf(f.x); wp[1]=f2bf(f.y); wp[2]=f2bf(f.z); wp[3]=f2bf(f.w);
      }
    } else {
      const u16* Ab = (const u16*)Aptr;
      #pragma unroll
      for (int j = 0; j < 8; ++j){
        int idx8 = t + j*256;
        int elem = idx8 << 3;
        int r = elem >> 7, c = elem & 127;
        int row = row0 + r; int arow = a_idx ? a_idx[row] : row;
        uint4 d = *(const uint4*)(Ab + (size_t)arow*K + kc + c);
        *(uint4*)&As[r][c] = d;
      }
    }
    // stage B transposed: each thread grabs 4 k-rows of one column
    #pragma unroll
    for (int j = 0; j < 16; ++j){
      int gi = t + j*256;
      int c = gi & 127;
      int k4 = (gi >> 7) << 2;
      size_t boff = (size_t)(kc + k4)*cfg.ldb + col0b + c;
      float f0 = Bp[boff];
      float f1 = Bp[boff + cfg.ldb];
      float f2 = Bp[boff + 2*(size_t)cfg.ldb];
      float f3 = Bp[boff + 3*(size_t)cfg.ldb];
      u16* wp = &Bs[c][k4];
      wp[0]=f2bf(f0); wp[1]=f2bf(f1); wp[2]=f2bf(f2); wp[3]=f2bf(f3);
    }
    __syncthreads();
    if (!ABF && cfg.dumpA && kc == 0){
      // coalesced dump of the converted/gathered bf16 A tile (fused gather+cast pass)
      #pragma unroll
      for (int j = 0; j < 8; ++j){
        int idx8 = t + j*256; int elem = idx8 << 3;
        int r = elem >> 7, c = elem & 127;
        uint4 d = *(const uint4*)&As[r][c];
        *(uint4*)(cfg.dumpA + (size_t)(row0+r)*K + c) = d;
      }
    }
    const int wm0 = wave*32;
    #pragma unroll
    for (int kk = 0; kk < 4; ++kk){
      shortx8 a0 = *(const shortx8*)&As[wm0 + l16][kk*32 + quad*8];
      shortx8 a1 = *(const shortx8*)&As[wm0 + 16 + l16][kk*32 + quad*8];
      #pragma unroll
      for (int nt = 0; nt < 8; ++nt){
        shortx8 bfr = *(const shortx8*)&Bs[nt*16 + l16][kk*32 + quad*8];
        acc[0][nt] = __builtin_amdgcn_mfma_f32_16x16x32_bf16(a0, bfr, acc[0][nt], 0, 0, 0);
        acc[1][nt] = __builtin_amdgcn_mfma_f32_16x16x32_bf16(a1, bfr, acc[1][nt], 0, 0, 0);
      }
    }
    __syncthreads();
  }
  const float* biasp = cfg.bias[cb];
  float* o32 = cfg.o32[cb];
  u16* o16 = cfg.o16[cb];
  const int col0o = cb * cfg.ocolmul;
  const int wm0 = wave*32;
  if (o16){
    // stage bf16 result in LDS (reuse As), then fully-coalesced 16B stores
    #pragma unroll
    for (int nt = 0; nt < 8; ++nt){
      int col = nt*16 + l16;
      float bvv = biasp ? biasp[col0o + col] : 0.0f;
      #pragma unroll
      for (int mt = 0; mt < 2; ++mt){
        #pragma unroll
        for (int r = 0; r < 4; ++r){
          float v = acc[mt][nt][r] + bvv;
          if (cfg.gelu) v = gelu_f(v);
          As[wm0 + mt*16 + quad*4 + r][col] = f2bf(v);
        }
      }
    }
    __syncthreads();
    #pragma unroll
    for (int j = 0; j < 8; ++j){
      int idx8 = t + j*256; int elem = idx8 << 3;
      int r = elem >> 7, c = elem & 127;
      uint4 d = *(const uint4*)&As[r][c];
      *(uint4*)(o16 + (size_t)(row0+r)*cfg.ld_out + col0o + c) = d;
    }
  }
  if (o32){
    float* psum = (float*)As;   // 128 floats, reuse LDS (safe: o16 path done or unused)
    if (cfg.pool){
      __syncthreads();
      if (t < 128) psum[t] = 0.f;
      __syncthreads();
    }
    #pragma unroll
    for (int nt = 0; nt < 8; ++nt){
      int col = col0o + nt*16 + l16;
      float bvv = biasp ? biasp[col] : 0.0f;
      float cs = 0.f;
      #pragma unroll
      for (int mt = 0; mt < 2; ++mt){
        #pragma unroll
        for (int r = 0; r < 4; ++r){
          int row = row0 + wm0 + mt*16 + quad*4 + r;
          float v = acc[mt][nt][r] + bvv;
          if (cfg.gelu) v = gelu_f(v);
          o32[(size_t)row * cfg.ld_out + col] = v;
          cs += v;
        }
      }
      if (cfg.pool) atomicAdd(&psum[nt*16 + l16], cs);
    }
    if (cfg.pool){
      __syncthreads();
      if (t < 128) atomicAdd(&cfg.pool[(row0 >> 9)*DDIM + t], psum[t] * (1.0f/NNODE));
    }
  }
}

// ---------------- attention: one wave per dst node, online softmax ----------------
__global__ __launch_bounds__(256)
void attn_kernel(const int* __restrict__ row_ptr, const int* __restrict__ ssrc,
                 const u16* __restrict__ e_rows,
                 const u16* __restrict__ qb, const u16* __restrict__ kb, const u16* __restrict__ vb,
                 const float* __restrict__ skip, float* __restrict__ y){
  int b = blockIdx.x;
  int xcd = b & 7, i = b >> 3;                // XCD swizzle: whole graph on one XCD for k/v L2 locality
  int g = xcd*8 + (i >> 7), slot = i & 127;
  int wave = threadIdx.x >> 6, lane = threadIdx.x & 63;
  int dst = g*NNODE + slot*4 + wave;
  const int ch = lane*2;                      // 2 channels per lane; head h = lanes 8h..8h+7
  ushort2 qp = *(const ushort2*)(qb + (size_t)dst*DDIM + ch);
  float q0 = bf2f(qp.x), q1 = bf2f(qp.y);
  int beg = row_ptr[dst], end = row_ptr[dst+1];
  float mh = -INFINITY, lh = 0.f, a0 = 0.f, a1 = 0.f;
  for (int idx = beg; idx < end; ++idx){
    int s = ssrc[idx];
    ushort2 ep = *(const ushort2*)(e_rows + (size_t)idx*DDIM + ch);
    ushort2 kp = *(const ushort2*)(kb + (size_t)s*DDIM + ch);
    ushort2 vp = *(const ushort2*)(vb + (size_t)s*DDIM + ch);
    float e0 = bf2f(ep.x), e1 = bf2f(ep.y);
    float p = q0*(bf2f(kp.x)+e0) + q1*(bf2f(kp.y)+e1);
    p += __shfl_xor(p, 1);
    p += __shfl_xor(p, 2);
    p += __shfl_xor(p, 4);                    // per-head dot over dh=16 (8 lanes x 2ch)
    float sc = p * 0.25f;                     // 1/sqrt(16)
    float mn = fmaxf(mh, sc);
    float cs = __expf(mh - mn), w = __expf(sc - mn);
    lh = lh*cs + w;
    a0 = a0*cs + w*(bf2f(vp.x)+e0);
    a1 = a1*cs + w*(bf2f(vp.y)+e1);
    mh = mn;
  }
  float r = lh > 0.f ? 1.0f/lh : 0.f;
  float2 sp = *(const float2*)(skip + (size_t)dst*DDIM + ch);
  float2 o; o.x = a0*r + sp.x; o.y = a1*r + sp.y;
  *(float2*)(y + (size_t)dst*DDIM + ch) = o;
}

// ---------------- GraphNorm (D=128 path): 4-way split partials + combine ----------------
__global__ __launch_bounds__(128)
void gstats_part(const float* __restrict__ y, float* __restrict__ ps, float* __restrict__ pq){
  int b = blockIdx.x, g = b >> 2, chunk = b & 3, c = threadIdx.x;
  const float* base = y + (size_t)g*NNODE*DDIM + (size_t)chunk*128*DDIM;
  float s = 0.f, q = 0.f;
  for (int i = 0; i < 128; ++i){
    float v = gelu_f(base[(size_t)i*DDIM + c]);
    s += v; q += v*v;
  }
  ps[b*DDIM + c] = s; pq[b*DDIM + c] = q;
}
__global__ __launch_bounds__(128)
void gstats_comb(const float* __restrict__ ps, const float* __restrict__ pq,
                 const float* __restrict__ alpha, float* __restrict__ meanb, float* __restrict__ invb){
  int g = blockIdx.x, c = threadIdx.x;
  float s = 0.f, q = 0.f;
  #pragma unroll
  for (int j = 0; j < 4; ++j){ s += ps[(g*4+j)*DDIM + c]; q += pq[(g*4+j)*DDIM + c]; }
  float mean = s * (1.f/NNODE);
  float msq  = q * (1.f/NNODE);
  float a = alpha[c];
  meanb[g*DDIM + c] = mean;
  invb[g*DDIM + c]  = rsqrtf(msq - mean*mean*a*(2.f-a) + EPSV);
}
__global__ void gnorm_kernel(const float* __restrict__ y, const float* __restrict__ meanb,
                             const float* __restrict__ invb, const float* __restrict__ gamma,
                             const float* __restrict__ beta, const float* __restrict__ alpha,
                             float* __restrict__ xout){
  int gid = blockIdx.x*256 + threadIdx.x;
  int c = gid & 127, node = gid >> 7, g = node >> 9;
  float v = gelu_f(y[gid]);
  xout[gid] = gamma[c]*(v - alpha[c]*meanb[g*DDIM+c])*invb[g*DDIM+c] + beta[c];
}

// ---------------- GraphNorm (Hff=512 path, bf16 data): 4-way split ----------------
__global__ __launch_bounds__(512)
void fstats_part(const u16* __restrict__ gb, float* __restrict__ ps, float* __restrict__ pq){
  int b = blockIdx.x, g = b >> 2, chunk = b & 3, c = threadIdx.x;
  const u16* base = gb + (size_t)g*NNODE*HFF + (size_t)chunk*128*HFF;
  float s = 0.f, q = 0.f;
  for (int i = 0; i < 128; ++i){
    float v = bf2f(base[(size_t)i*HFF + c]);
    s += v; q += v*v;
  }
  ps[b*HFF + c] = s; pq[b*HFF + c] = q;
}
__global__ __launch_bounds__(512)
void fstats_comb(const float* __restrict__ ps, const float* __restrict__ pq,
                 const float* __restrict__ alpha, float* __restrict__ meanb, float* __restrict__ invb){
  int g = blockIdx.x, c = threadIdx.x;
  float s = 0.f, q = 0.f;
  #pragma unroll
  for (int j = 0; j < 4; ++j){ s += ps[(g*4+j)*HFF + c]; q += pq[(g*4+j)*HFF + c]; }
  float mean = s * (1.f/NNODE);
  float msq  = q * (1.f/NNODE);
  float a = alpha[c];
  meanb[g*HFF + c] = mean;
  invb[g*HFF + c]  = rsqrtf(msq - mean*mean*a*(2.f-a) + EPSV);
}
__global__ void fnorm_kernel(const u16* __restrict__ gb, const float* __restrict__ meanb,
                             const float* __restrict__ invb, const float* __restrict__ gamma,
                             const float* __restrict__ beta, const float* __restrict__ alpha,
                             u16* __restrict__ hn){
  int gid = blockIdx.x*256 + threadIdx.x;
  int c = gid & (HFF-1); int node = gid >> 9; int g = node >> 9;
  float v = bf2f(gb[gid]);
  hn[gid] = f2bf(gamma[c]*(v - alpha[c]*meanb[g*HFF+c])*invb[g*HFF+c] + beta[c]);
}

extern "C" void kernel_launch(void* const* d_in, const int* in_sizes, int n_in,
                              void* d_out, int out_size, void* d_ws, size_t ws_size,
                              hipStream_t stream){
  const float* x_in = (const float*)d_in[0];
  const int*   eidx = (const int*)d_in[1];
  const float* ea   = (const float*)d_in[2];
  const float* Wq   = (const float*)d_in[4];
  const float* bq   = (const float*)d_in[5];
  const float* Wk   = (const float*)d_in[6];
  const float* bk   = (const float*)d_in[7];
  const float* Wv   = (const float*)d_in[8];
  const float* bv   = (const float*)d_in[9];
  const float* We   = (const float*)d_in[10];
  const float* Wsk  = (const float*)d_in[11];
  const float* bsk  = (const float*)d_in[12];
  const float* gn_g = (const float*)d_in[13];
  const float* gn_b = (const float*)d_in[14];
  const float* gn_a = (const float*)d_in[15];
  const float* ffW1 = (const float*)d_in[16];
  const float* ffb1 = (const float*)d_in[17];
  const float* fgn_g= (const float*)d_in[18];
  const float* fgn_b= (const float*)d_in[19];
  const float* fgn_a= (const float*)d_in[20];
  const float* ffW2 = (const float*)d_in[21];
  const float* ffb2 = (const float*)d_in[22];
  const int* srcA = eidx;
  const int* dstA = eidx + NEDGE;

  char* w = (char*)d_ws;
  auto alloc = [&](size_t bytes)->char*{ char* p = w; w += (bytes + 255) & ~(size_t)255; return p; };
  int* counts  = (int*)alloc((size_t)NTOT*4);
  int* row_ptr = (int*)alloc((size_t)(NTOT+1)*4);
  int* ssrc    = (int*)alloc((size_t)NEDGE*4);
  int* seid    = (int*)alloc((size_t)NEDGE*4);
  u16* e_bf    = (u16*)alloc((size_t)NEDGE*DDIM*2);   // 128 MiB; reused as g/hn-part in FFN phase
  u16* ea_s    = (u16*)alloc((size_t)NEDGE*DDIM*2);   // 128 MiB; dst-sorted bf16 edge_attr
  u16* qb      = (u16*)alloc((size_t)NTOT*DDIM*2);
  u16* kb      = (u16*)alloc((size_t)NTOT*DDIM*2);
  u16* vb      = (u16*)alloc((size_t)NTOT*DDIM*2);
  float* skipb = (float*)alloc((size_t)NTOT*DDIM*4);
  float* yb    = (float*)alloc((size_t)NTOT*DDIM*4);
  float* xcur  = (float*)alloc((size_t)NTOT*DDIM*4);
  float* meanb = (float*)alloc((size_t)NB*HFF*4);
  float* invb  = (float*)alloc((size_t)NB*HFF*4);
  float* psbuf = (float*)alloc((size_t)NB*4*HFF*4);
  float* pqbuf = (float*)alloc((size_t)NB*4*HFF*4);
  u16* g_bf  = e_bf;                                  // alias (e dead by FFN phase)
  u16* hn_bf = e_bf + (size_t)NTOT*HFF;

  // CSR build (same every call)
  zero_kernel<<<NTOT/256, 256, 0, stream>>>(counts, NTOT);
  hist_kernel<<<NEDGE/256, 256, 0, stream>>>(dstA, counts);
  scan_kernel<<<1, 1024, 0, stream>>>(counts, row_ptr, counts);
  scatter_kernel<<<NEDGE/256, 256, 0, stream>>>(srcA, dstA, counts, ssrc, seid);

  const float* x_l = x_in;
  for (int l = 0; l < 3; ++l){
    // e = ea_sorted @ We[l] -> bf16. Layer 0: gather+cast from fp32 ea (dumping bf16 sorted copy);
    // layers 1,2: sequential bf16 reads of the dumped copy.
    GemmCfg ce = {};
    for (int i2 = 0; i2 < 4; ++i2){ ce.B[i2] = We + (size_t)l*DDIM*DDIM; ce.o16[i2] = e_bf; }
    ce.ldb = DDIM; ce.ld_out = DDIM; ce.K = DDIM; ce.bcolmul = 0; ce.ocolmul = 0; ce.gelu = 0;
    if (l == 0){
      ce.dumpA = ea_s;
      gemm_kernel<false><<<dim3(NEDGE/128, 1), 256, 0, stream>>>(ea, seid, ce);
    } else {
      gemm_kernel<true><<<dim3(NEDGE/128, 1), 256, 0, stream>>>(ea_s, nullptr, ce);
    }

    // q,k,v (bf16) + skip (fp32) fused: grid.y picks the weight
    GemmCfg cq = {};
    cq.B[0]=Wq + (size_t)l*DDIM*DDIM; cq.B[1]=Wk + (size_t)l*DDIM*DDIM;
    cq.B[2]=Wv + (size_t)l*DDIM*DDIM; cq.B[3]=Wsk + (size_t)l*DDIM*DDIM;
    cq.bias[0]=bq + l*DDIM; cq.bias[1]=bk + l*DDIM; cq.bias[2]=bv + l*DDIM; cq.bias[3]=bsk + l*DDIM;
    cq.o16[0]=qb; cq.o16[1]=kb; cq.o16[2]=vb; cq.o16[3]=nullptr;
    cq.o32[3]=skipb;
    cq.ldb = DDIM; cq.ld_out = DDIM; cq.K = DDIM; cq.bcolmul = 0; cq.ocolmul = 0; cq.gelu = 0;
    gemm_kernel<false><<<dim3(NTOT/128, 4), 256, 0, stream>>>(x_l, nullptr, cq);

    attn_kernel<<<NTOT/4, 256, 0, stream>>>(row_ptr, ssrc, e_bf, qb, kb, vb, skipb, yb);

    if (l < 2){
      gstats_part<<<NB*4, 128, 0, stream>>>(yb, psbuf, pqbuf);
      gstats_comb<<<NB, 128, 0, stream>>>(psbuf, pqbuf, gn_a + l*DDIM, meanb, invb);
      gnorm_kernel<<<NTOT*DDIM/256, 256, 0, stream>>>(yb, meanb, invb,
          gn_g + l*DDIM, gn_b + l*DDIM, gn_a + l*DDIM, xcur);
      x_l = xcur;
    }
  }

  // FFN: g = gelu(y @ ffW1 + ffb1)  (bf16, aliases e region)
  GemmCfg c1 = {};
  for (int i2 = 0; i2 < 4; ++i2){ c1.B[i2] = ffW1; c1.bias[i2] = ffb1; c1.o16[i2] = g_bf; }
  c1.ldb = HFF; c1.ld_out = HFF; c1.K = DDIM; c1.bcolmul = 128; c1.ocolmul = 128; c1.gelu = 1;
  gemm_kernel<false><<<dim3(NTOT/128, 4), 256, 0, stream>>>(yb, nullptr, c1);

  fstats_part<<<NB*4, 512, 0, stream>>>(g_bf, psbuf, pqbuf);
  fstats_comb<<<NB, 512, 0, stream>>>(psbuf, pqbuf, fgn_a, meanb, invb);
  fnorm_kernel<<<NTOT*HFF/256, 256, 0, stream>>>(g_bf, meanb, invb, fgn_g, fgn_b, fgn_a, hn_bf);

  // x_out = hn @ ffW2 + ffb2 -> d_out (node embeddings, fp32) with fused mean-pool
  zerof_kernel<<<NB*DDIM/256, 256, 0, stream>>>((float*)d_out + (size_t)NTOT*DDIM, NB*DDIM);
  GemmCfg c2 = {};
  for (int i2 = 0; i2 < 4; ++i2){ c2.B[i2] = ffW2; c2.bias[i2] = ffb2; c2.o32[i2] = (float*)d_out; }
  c2.ldb = DDIM; c2.ld_out = DDIM; c2.K = HFF; c2.bcolmul = 0; c2.ocolmul = 0; c2.gelu = 0;
  c2.pool = (float*)d_out + (size_t)NTOT*DDIM;
  gemm_kernel<true><<<dim3(NTOT/128, 1), 256, 0, stream>>>(hn_bf, nullptr, c2);
}

// Round 3
// 1200.199 us; speedup vs baseline: 1.7642x; 1.5087x over previous
//
#include <hip/hip_runtime.h>
#include <hip/hip_bf16.h>
#include <math.h>

typedef unsigned short u16;
typedef __attribute__((ext_vector_type(4))) float floatx4;
typedef __attribute__((ext_vector_type(8))) short shortx8;

#define NB 64
#define NNODE 512
#define NTOT (NB*NNODE)      // 32768
#define DDIM 128
#define DEG 16
#define NEDGE (NTOT*DEG)     // 524288
#define HFF 512
#define EPSV 1e-5f
#define BFRAG_U16 16384      // 32 KB B-fragment region (u16 units)
#define EPI_LD 136           // padded epilogue row stride (u16)

__device__ __forceinline__ float bf2f(u16 u){
  union { unsigned int i; float f; } v; v.i = ((unsigned int)u) << 16; return v.f;
}
__device__ __forceinline__ u16 f2bf(float f){
  union { float f; unsigned int i; } v; v.f = f;
  unsigned int r = v.i + 0x7FFFu + ((v.i >> 16) & 1u);
  return (u16)(r >> 16);
}
__device__ __forceinline__ float gelu_f(float x){
  return 0.5f * x * (1.0f + erff(x * 0.70710678118654752f));
}

// ---------------- CSR build (dst-sorted) ----------------
__global__ void zero_kernel(int* p, int n){
  int i = blockIdx.x*256 + threadIdx.x; if (i < n) p[i] = 0;
}
__global__ void zerof_kernel(float* p, int n){
  int i = blockIdx.x*256 + threadIdx.x; if (i < n) p[i] = 0.f;
}
__global__ void hist_kernel(const int* __restrict__ dst, int* __restrict__ counts){
  int e = blockIdx.x*256 + threadIdx.x; atomicAdd(&counts[dst[e]], 1);
}
__global__ void scan_kernel(const int* counts, int* row_ptr, int* cursor){
  __shared__ int part[1024];
  int t = threadIdx.x; int base = t*32;
  int loc[32]; int s = 0;
  #pragma unroll
  for (int i = 0; i < 32; ++i){ loc[i] = counts[base+i]; s += loc[i]; }
  part[t] = s; __syncthreads();
  for (int off = 1; off < 1024; off <<= 1){
    int v = (t >= off) ? part[t-off] : 0;
    __syncthreads(); part[t] += v; __syncthreads();
  }
  int run = part[t] - s;
  #pragma unroll
  for (int i = 0; i < 32; ++i){ row_ptr[base+i] = run; cursor[base+i] = run; run += loc[i]; }
  if (t == 0) row_ptr[NTOT] = part[1023];
}
__global__ void scatter_kernel(const int* __restrict__ src, const int* __restrict__ dst,
                               int* __restrict__ cursor, int* __restrict__ ssrc, int* __restrict__ seid){
  int e = blockIdx.x*256 + threadIdx.x;
  int d = dst[e];
  int pos = atomicAdd(&cursor[d], 1);
  ssrc[pos] = src[e]; seid[pos] = e;
}
__global__ void castx_kernel(const float* __restrict__ x, u16* __restrict__ xb){
  int i = (blockIdx.x*256 + threadIdx.x)*4;
  float4 f = *(const float4*)(x + i);
  ushort4 o; o.x = f2bf(f.x); o.y = f2bf(f.y); o.z = f2bf(f.z); o.w = f2bf(f.w);
  *(ushort4*)(xb + i) = o;
}

// ---------------- K=128 barrier-free persistent GEMM ----------------
// B staged once to LDS in fragment layout; A frags direct from global; waves independent.
struct Gemm2Cfg {
  const float* B[4];
  const float* bias[4];
  float* o32[4];
  u16* o16[4];
  u16* dumpA;          // fp32-A path: also store converted A (row-major bf16, sorted order)
  const int* a_idx;    // optional row gather
  int ldb, ld_out, bcolmul, ocolmul, gelu, mtiles;
};

template<bool ABF>
__global__ __launch_bounds__(256, 3)
void gemm2_kernel(const void* __restrict__ Aptr, Gemm2Cfg cfg){
  __shared__ u16 lds[BFRAG_U16 + 4*16*EPI_LD];   // 32 KB B + 4x4.25 KB per-wave epilogue
  const int t = threadIdx.x;
  const int wave = t >> 6, lane = t & 63, quad = lane >> 4, l16 = lane & 15;
  const int cb = blockIdx.y;
  const float* Bp = cfg.B[cb];
  const int col0b = cb * cfg.bcolmul;
  // stage B fragments: wave w handles kk=w, nt=0..7
  {
    const int kk = wave;
    #pragma unroll
    for (int nt = 0; nt < 8; ++nt){
      int colB = col0b + nt*16 + l16;
      shortx8 pk;
      #pragma unroll
      for (int j = 0; j < 8; ++j)
        pk[j] = (short)f2bf(Bp[(size_t)(kk*32 + quad*8 + j)*cfg.ldb + colB]);
      *(shortx8*)&lds[((kk*8 + nt)*64 + lane)*8] = pk;
    }
  }
  __syncthreads();
  const float* biasp = cfg.bias[cb];
  const int col0o = cb * cfg.ocolmul;
  float bias_r[8];
  #pragma unroll
  for (int nt = 0; nt < 8; ++nt)
    bias_r[nt] = biasp ? biasp[col0o + nt*16 + l16] : 0.0f;
  u16* epi = &lds[BFRAG_U16 + wave*16*EPI_LD];

  for (int tile = blockIdx.x; tile < cfg.mtiles; tile += gridDim.x){
    const int wrow0 = tile*128 + wave*32;
    const int r0 = wrow0 + l16, r1 = wrow0 + 16 + l16;
    const long ar0 = cfg.a_idx ? (long)cfg.a_idx[r0] : (long)r0;
    const long ar1 = cfg.a_idx ? (long)cfg.a_idx[r1] : (long)r1;
    shortx8 af[2][4];
    if (ABF){
      const u16* Ab = (const u16*)Aptr;
      #pragma unroll
      for (int kk = 0; kk < 4; ++kk){
        af[0][kk] = *(const shortx8*)(Ab + ar0*128 + kk*32 + quad*8);
        af[1][kk] = *(const shortx8*)(Ab + ar1*128 + kk*32 + quad*8);
      }
    } else {
      const float* Af = (const float*)Aptr;
      #pragma unroll
      for (int kk = 0; kk < 4; ++kk){
        float4 x0 = *(const float4*)(Af + ar0*128 + kk*32 + quad*8);
        float4 x1 = *(const float4*)(Af + ar0*128 + kk*32 + quad*8 + 4);
        float4 y0 = *(const float4*)(Af + ar1*128 + kk*32 + quad*8);
        float4 y1 = *(const float4*)(Af + ar1*128 + kk*32 + quad*8 + 4);
        shortx8 a0, a1;
        a0[0]=(short)f2bf(x0.x); a0[1]=(short)f2bf(x0.y); a0[2]=(short)f2bf(x0.z); a0[3]=(short)f2bf(x0.w);
        a0[4]=(short)f2bf(x1.x); a0[5]=(short)f2bf(x1.y); a0[6]=(short)f2bf(x1.z); a0[7]=(short)f2bf(x1.w);
        a1[0]=(short)f2bf(y0.x); a1[1]=(short)f2bf(y0.y); a1[2]=(short)f2bf(y0.z); a1[3]=(short)f2bf(y0.w);
        a1[4]=(short)f2bf(y1.x); a1[5]=(short)f2bf(y1.y); a1[6]=(short)f2bf(y1.z); a1[7]=(short)f2bf(y1.w);
        af[0][kk] = a0; af[1][kk] = a1;
      }
      if (cfg.dumpA){
        #pragma unroll
        for (int kk = 0; kk < 4; ++kk){
          *(shortx8*)(cfg.dumpA + (size_t)r0*128 + kk*32 + quad*8) = af[0][kk];
          *(shortx8*)(cfg.dumpA + (size_t)r1*128 + kk*32 + quad*8) = af[1][kk];
        }
      }
    }
    floatx4 acc[2][8] = {};
    #pragma unroll
    for (int kk = 0; kk < 4; ++kk){
      #pragma unroll
      for (int nt = 0; nt < 8; ++nt){
        shortx8 bfr = *(const shortx8*)&lds[((kk*8 + nt)*64 + lane)*8];
        acc[0][nt] = __builtin_amdgcn_mfma_f32_16x16x32_bf16(af[0][kk], bfr, acc[0][nt], 0, 0, 0);
        acc[1][nt] = __builtin_amdgcn_mfma_f32_16x16x32_bf16(af[1][kk], bfr, acc[1][nt], 0, 0, 0);
      }
    }
    u16* o16 = cfg.o16[cb];
    if (o16){
      #pragma unroll
      for (int mt = 0; mt < 2; ++mt){
        #pragma unroll
        for (int nt = 0; nt < 8; ++nt){
          #pragma unroll
          for (int r = 0; r < 4; ++r){
            float v = acc[mt][nt][r] + bias_r[nt];
            if (cfg.gelu) v = gelu_f(v);
            epi[(quad*4 + r)*EPI_LD + nt*16 + l16] = f2bf(v);
          }
        }
        #pragma unroll
        for (int j = 0; j < 4; ++j){
          int row = j*4 + quad;
          uint4 d = *(const uint4*)&epi[row*EPI_LD + l16*8];
          *(uint4*)(o16 + (size_t)(wrow0 + mt*16 + row)*cfg.ld_out + col0o + l16*8) = d;
        }
      }
    } else {
      float* o32 = cfg.o32[cb];
      #pragma unroll
      for (int nt = 0; nt < 8; ++nt){
        #pragma unroll
        for (int mt = 0; mt < 2; ++mt){
          #pragma unroll
          for (int r = 0; r < 4; ++r){
            int row = wrow0 + mt*16 + quad*4 + r;
            float v = acc[mt][nt][r] + bias_r[nt];
            if (cfg.gelu) v = gelu_f(v);
            o32[(size_t)row*cfg.ld_out + col0o + nt*16 + l16] = v;
          }
        }
      }
    }
  }
}

// ---------------- old K-looped GEMM (kept for FFN2, K=512) ----------------
struct GemmCfg {
  const float* B[4];
  const float* bias[4];
  float* o32[4];
  u16* o16[4];
  float* pool;
  int ldb, ld_out, K, bcolmul, ocolmul, gelu;
};

__global__ __launch_bounds__(256, 2)
void gemm_old(const u16* __restrict__ Ab, GemmCfg cfg){
  __shared__ u16 As[128][136];
  __shared__ u16 Bs[128][136];
  const int t = threadIdx.x;
  const int wave = t >> 6, lane = t & 63, quad = lane >> 4, l16 = lane & 15;
  const int row0 = blockIdx.x * 128;
  const int cb = blockIdx.y;
  const float* Bp = cfg.B[cb];
  const int col0b = cb * cfg.bcolmul;
  const int K = cfg.K;
  floatx4 acc[2][8] = {};
  for (int kc = 0; kc < K; kc += 128){
    #pragma unroll
    for (int j = 0; j < 8; ++j){
      int idx8 = t + j*256;
      int elem = idx8 << 3;
      int r = elem >> 7, c = elem & 127;
      uint4 d = *(const uint4*)(Ab + (size_t)(row0+r)*K + kc + c);
      *(uint4*)&As[r][c] = d;
    }
    #pragma unroll
    for (int j = 0; j < 16; ++j){
      int gi = t + j*256;
      int c = gi & 127;
      int k4 = (gi >> 7) << 2;
      size_t boff = (size_t)(kc + k4)*cfg.ldb + col0b + c;
      float f0 = Bp[boff];
      float f1 = Bp[boff + cfg.ldb];
      float f2 = Bp[boff + 2*(size_t)cfg.ldb];
      float f3 = Bp[boff + 3*(size_t)cfg.ldb];
      u16* wp = &Bs[c][k4];
      wp[0]=f2bf(f0); wp[1]=f2bf(f1); wp[2]=f2bf(f2); wp[3]=f2bf(f3);
    }
    __syncthreads();
    const int wm0 = wave*32;
    #pragma unroll
    for (int kk = 0; kk < 4; ++kk){
      shortx8 a0 = *(const shortx8*)&As[wm0 + l16][kk*32 + quad*8];
      shortx8 a1 = *(const shortx8*)&As[wm0 + 16 + l16][kk*32 + quad*8];
      #pragma unroll
      for (int nt = 0; nt < 8; ++nt){
        shortx8 bfr = *(const shortx8*)&Bs[nt*16 + l16][kk*32 + quad*8];
        acc[0][nt] = __builtin_amdgcn_mfma_f32_16x16x32_bf16(a0, bfr, acc[0][nt], 0, 0, 0);
        acc[1][nt] = __builtin_amdgcn_mfma_f32_16x16x32_bf16(a1, bfr, acc[1][nt], 0, 0, 0);
      }
    }
    __syncthreads();
  }
  const float* biasp = cfg.bias[cb];
  float* o32 = cfg.o32[cb];
  const int col0o = cb * cfg.ocolmul;
  const int wm0 = wave*32;
  float* psum = (float*)As;
  if (cfg.pool){
    __syncthreads();
    if (t < 128) psum[t] = 0.f;
    __syncthreads();
  }
  #pragma unroll
  for (int nt = 0; nt < 8; ++nt){
    int col = col0o + nt*16 + l16;
    float bvv = biasp ? biasp[col] : 0.0f;
    float cs = 0.f;
    #pragma unroll
    for (int mt = 0; mt < 2; ++mt){
      #pragma unroll
      for (int r = 0; r < 4; ++r){
        int row = row0 + wm0 + mt*16 + quad*4 + r;
        float v = acc[mt][nt][r] + bvv;
        if (cfg.gelu) v = gelu_f(v);
        o32[(size_t)row * cfg.ld_out + col] = v;
        cs += v;
      }
    }
    if (cfg.pool) atomicAdd(&psum[nt*16 + l16], cs);
  }
  if (cfg.pool){
    __syncthreads();
    if (t < 128) atomicAdd(&cfg.pool[(row0 >> 9)*DDIM + t], psum[t] * (1.0f/NNODE));
  }
}

// ---------------- attention: one wave per dst node, online softmax ----------------
__global__ __launch_bounds__(256)
void attn_kernel(const int* __restrict__ row_ptr, const int* __restrict__ ssrc,
                 const u16* __restrict__ e_rows,
                 const u16* __restrict__ qb, const u16* __restrict__ kb, const u16* __restrict__ vb,
                 const float* __restrict__ skip, float* __restrict__ y){
  int b = blockIdx.x;
  int xcd = b & 7, i = b >> 3;
  int g = xcd*8 + (i >> 7), slot = i & 127;
  int wave = threadIdx.x >> 6, lane = threadIdx.x & 63;
  int dst = g*NNODE + slot*4 + wave;
  const int ch = lane*2;
  ushort2 qp = *(const ushort2*)(qb + (size_t)dst*DDIM + ch);
  float q0 = bf2f(qp.x), q1 = bf2f(qp.y);
  int beg = row_ptr[dst], end = row_ptr[dst+1];
  float mh = -INFINITY, lh = 0.f, a0 = 0.f, a1 = 0.f;
  for (int idx = beg; idx < end; ++idx){
    int s = ssrc[idx];
    ushort2 ep = *(const ushort2*)(e_rows + (size_t)idx*DDIM + ch);
    ushort2 kp = *(const ushort2*)(kb + (size_t)s*DDIM + ch);
    ushort2 vp = *(const ushort2*)(vb + (size_t)s*DDIM + ch);
    float e0 = bf2f(ep.x), e1 = bf2f(ep.y);
    float p = q0*(bf2f(kp.x)+e0) + q1*(bf2f(kp.y)+e1);
    p += __shfl_xor(p, 1);
    p += __shfl_xor(p, 2);
    p += __shfl_xor(p, 4);
    float sc = p * 0.25f;
    float mn = fmaxf(mh, sc);
    float cs = __expf(mh - mn), w = __expf(sc - mn);
    lh = lh*cs + w;
    a0 = a0*cs + w*(bf2f(vp.x)+e0);
    a1 = a1*cs + w*(bf2f(vp.y)+e1);
    mh = mn;
  }
  float r = lh > 0.f ? 1.0f/lh : 0.f;
  float2 sp = *(const float2*)(skip + (size_t)dst*DDIM + ch);
  float2 o; o.x = a0*r + sp.x; o.y = a1*r + sp.y;
  *(float2*)(y + (size_t)dst*DDIM + ch) = o;
}

// ---------------- GraphNorm (D=128): 4-way split partials + combine; bf16 output ----------------
__global__ __launch_bounds__(128)
void gstats_part(const float* __restrict__ y, float* __restrict__ ps, float* __restrict__ pq){
  int b = blockIdx.x, g = b >> 2, chunk = b & 3, c = threadIdx.x;
  const float* base = y + (size_t)g*NNODE*DDIM + (size_t)chunk*128*DDIM;
  float s = 0.f, q = 0.f;
  for (int i = 0; i < 128; ++i){
    float v = gelu_f(base[(size_t)i*DDIM + c]);
    s += v; q += v*v;
  }
  ps[b*DDIM + c] = s; pq[b*DDIM + c] = q;
}
__global__ __launch_bounds__(128)
void gstats_comb(const float* __restrict__ ps, const float* __restrict__ pq,
                 const float* __restrict__ alpha, float* __restrict__ meanb, float* __restrict__ invb){
  int g = blockIdx.x, c = threadIdx.x;
  float s = 0.f, q = 0.f;
  #pragma unroll
  for (int j = 0; j < 4; ++j){ s += ps[(g*4+j)*DDIM + c]; q += pq[(g*4+j)*DDIM + c]; }
  float mean = s * (1.f/NNODE);
  float msq  = q * (1.f/NNODE);
  float a = alpha[c];
  meanb[g*DDIM + c] = mean;
  invb[g*DDIM + c]  = rsqrtf(msq - mean*mean*a*(2.f-a) + EPSV);
}
__global__ void gnorm_kernel(const float* __restrict__ y, const float* __restrict__ meanb,
                             const float* __restrict__ invb, const float* __restrict__ gamma,
                             const float* __restrict__ beta, const float* __restrict__ alpha,
                             u16* __restrict__ xout){
  int gid = blockIdx.x*256 + threadIdx.x;
  int c = gid & 127, node = gid >> 7, g = node >> 9;
  float v = gelu_f(y[gid]);
  xout[gid] = f2bf(gamma[c]*(v - alpha[c]*meanb[g*DDIM+c])*invb[g*DDIM+c] + beta[c]);
}

// ---------------- GraphNorm (Hff=512, bf16 data): 4-way split ----------------
__global__ __launch_bounds__(512)
void fstats_part(const u16* __restrict__ gb, float* __restrict__ ps, float* __restrict__ pq){
  int b = blockIdx.x, g = b >> 2, chunk = b & 3, c = threadIdx.x;
  const u16* base = gb + (size_t)g*NNODE*HFF + (size_t)chunk*128*HFF;
  float s = 0.f, q = 0.f;
  for (int i = 0; i < 128; ++i){
    float v = bf2f(base[(size_t)i*HFF + c]);
    s += v; q += v*v;
  }
  ps[b*HFF + c] = s; pq[b*HFF + c] = q;
}
__global__ __launch_bounds__(512)
void fstats_comb(const float* __restrict__ ps, const float* __restrict__ pq,
                 const float* __restrict__ alpha, float* __restrict__ meanb, float* __restrict__ invb){
  int g = blockIdx.x, c = threadIdx.x;
  float s = 0.f, q = 0.f;
  #pragma unroll
  for (int j = 0; j < 4; ++j){ s += ps[(g*4+j)*HFF + c]; q += pq[(g*4+j)*HFF + c]; }
  float mean = s * (1.f/NNODE);
  float msq  = q * (1.f/NNODE);
  float a = alpha[c];
  meanb[g*HFF + c] = mean;
  invb[g*HFF + c]  = rsqrtf(msq - mean*mean*a*(2.f-a) + EPSV);
}
__global__ void fnorm_kernel(const u16* __restrict__ gb, const float* __restrict__ meanb,
                             const float* __restrict__ invb, const float* __restrict__ gamma,
                             const float* __restrict__ beta, const float* __restrict__ alpha,
                             u16* __restrict__ hn){
  int gid = blockIdx.x*256 + threadIdx.x;
  int c = gid & (HFF-1); int node = gid >> 9; int g = node >> 9;
  float v = bf2f(gb[gid]);
  hn[gid] = f2bf(gamma[c]*(v - alpha[c]*meanb[g*HFF+c])*invb[g*HFF+c] + beta[c]);
}

extern "C" void kernel_launch(void* const* d_in, const int* in_sizes, int n_in,
                              void* d_out, int out_size, void* d_ws, size_t ws_size,
                              hipStream_t stream){
  const float* x_in = (const float*)d_in[0];
  const int*   eidx = (const int*)d_in[1];
  const float* ea   = (const float*)d_in[2];
  const float* Wq   = (const float*)d_in[4];
  const float* bq   = (const float*)d_in[5];
  const float* Wk   = (const float*)d_in[6];
  const float* bk   = (const float*)d_in[7];
  const float* Wv   = (const float*)d_in[8];
  const float* bv   = (const float*)d_in[9];
  const float* We   = (const float*)d_in[10];
  const float* Wsk  = (const float*)d_in[11];
  const float* bsk  = (const float*)d_in[12];
  const float* gn_g = (const float*)d_in[13];
  const float* gn_b = (const float*)d_in[14];
  const float* gn_a = (const float*)d_in[15];
  const float* ffW1 = (const float*)d_in[16];
  const float* ffb1 = (const float*)d_in[17];
  const float* fgn_g= (const float*)d_in[18];
  const float* fgn_b= (const float*)d_in[19];
  const float* fgn_a= (const float*)d_in[20];
  const float* ffW2 = (const float*)d_in[21];
  const float* ffb2 = (const float*)d_in[22];
  const int* srcA = eidx;
  const int* dstA = eidx + NEDGE;

  char* w = (char*)d_ws;
  auto alloc = [&](size_t bytes)->char*{ char* p = w; w += (bytes + 255) & ~(size_t)255; return p; };
  int* counts  = (int*)alloc((size_t)NTOT*4);
  int* row_ptr = (int*)alloc((size_t)(NTOT+1)*4);
  int* ssrc    = (int*)alloc((size_t)NEDGE*4);
  int* seid    = (int*)alloc((size_t)NEDGE*4);
  u16* e_bf    = (u16*)alloc((size_t)NEDGE*DDIM*2);   // 128 MiB; reused as g/hn in FFN phase
  u16* ea_s    = (u16*)alloc((size_t)NEDGE*DDIM*2);   // 128 MiB; dst-sorted bf16 edge_attr
  u16* x_bf    = (u16*)alloc((size_t)NTOT*DDIM*2);    // bf16 layer input (x / gnorm output)
  u16* qb      = (u16*)alloc((size_t)NTOT*DDIM*2);
  u16* kb      = (u16*)alloc((size_t)NTOT*DDIM*2);
  u16* vb      = (u16*)alloc((size_t)NTOT*DDIM*2);
  float* skipb = (float*)alloc((size_t)NTOT*DDIM*4);
  float* yb    = (float*)alloc((size_t)NTOT*DDIM*4);
  float* meanb = (float*)alloc((size_t)NB*HFF*4);
  float* invb  = (float*)alloc((size_t)NB*HFF*4);
  float* psbuf = (float*)alloc((size_t)NB*4*HFF*4);
  float* pqbuf = (float*)alloc((size_t)NB*4*HFF*4);
  u16* g_bf  = e_bf;
  u16* hn_bf = e_bf + (size_t)NTOT*HFF;

  // CSR build + x cast
  zero_kernel<<<NTOT/256, 256, 0, stream>>>(counts, NTOT);
  hist_kernel<<<NEDGE/256, 256, 0, stream>>>(dstA, counts);
  scan_kernel<<<1, 1024, 0, stream>>>(counts, row_ptr, counts);
  scatter_kernel<<<NEDGE/256, 256, 0, stream>>>(srcA, dstA, counts, ssrc, seid);
  castx_kernel<<<NTOT*DDIM/1024, 256, 0, stream>>>(x_in, x_bf);

  for (int l = 0; l < 3; ++l){
    // e = ea_sorted @ We[l] -> bf16 (layer 0: gather+cast fp32 ea, dump sorted bf16 copy)
    Gemm2Cfg ce = {};
    ce.B[0] = We + (size_t)l*DDIM*DDIM; ce.o16[0] = e_bf;
    ce.ldb = DDIM; ce.ld_out = DDIM; ce.bcolmul = 0; ce.ocolmul = 0; ce.gelu = 0;
    ce.mtiles = NEDGE/128;
    if (l == 0){
      ce.dumpA = ea_s; ce.a_idx = seid;
      gemm2_kernel<false><<<dim3(1024, 1), 256, 0, stream>>>(ea, ce);
    } else {
      gemm2_kernel<true><<<dim3(1024, 1), 256, 0, stream>>>(ea_s, ce);
    }

    // q,k,v (bf16) + skip (fp32), grid.y picks weight; A = bf16 x
    Gemm2Cfg cq = {};
    cq.B[0]=Wq + (size_t)l*DDIM*DDIM; cq.B[1]=Wk + (size_t)l*DDIM*DDIM;
    cq.B[2]=Wv + (size_t)l*DDIM*DDIM; cq.B[3]=Wsk + (size_t)l*DDIM*DDIM;
    cq.bias[0]=bq + l*DDIM; cq.bias[1]=bk + l*DDIM; cq.bias[2]=bv + l*DDIM; cq.bias[3]=bsk + l*DDIM;
    cq.o16[0]=qb; cq.o16[1]=kb; cq.o16[2]=vb; cq.o16[3]=nullptr;
    cq.o32[3]=skipb;
    cq.ldb = DDIM; cq.ld_out = DDIM; cq.bcolmul = 0; cq.ocolmul = 0; cq.gelu = 0;
    cq.mtiles = NTOT/128;
    gemm2_kernel<true><<<dim3(NTOT/128, 4), 256, 0, stream>>>(x_bf, cq);

    attn_kernel<<<NTOT/4, 256, 0, stream>>>(row_ptr, ssrc, e_bf, qb, kb, vb, skipb, yb);

    if (l < 2){
      gstats_part<<<NB*4, 128, 0, stream>>>(yb, psbuf, pqbuf);
      gstats_comb<<<NB, 128, 0, stream>>>(psbuf, pqbuf, gn_a + l*DDIM, meanb, invb);
      gnorm_kernel<<<NTOT*DDIM/256, 256, 0, stream>>>(yb, meanb, invb,
          gn_g + l*DDIM, gn_b + l*DDIM, gn_a + l*DDIM, x_bf);
    }
  }

  // FFN1: g = gelu(y @ ffW1 + ffb1) (bf16, aliases e region); A fp32 = yb
  Gemm2Cfg c1 = {};
  for (int i2 = 0; i2 < 4; ++i2){ c1.B[i2] = ffW1; c1.bias[i2] = ffb1; c1.o16[i2] = g_bf; }
  c1.ldb = HFF; c1.ld_out = HFF; c1.bcolmul = 128; c1.ocolmul = 128; c1.gelu = 1;
  c1.mtiles = NTOT/128;
  gemm2_kernel<false><<<dim3(NTOT/128, 4), 256, 0, stream>>>(yb, c1);

  fstats_part<<<NB*4, 512, 0, stream>>>(g_bf, psbuf, pqbuf);
  fstats_comb<<<NB, 512, 0, stream>>>(psbuf, pqbuf, fgn_a, meanb, invb);
  fnorm_kernel<<<NTOT*HFF/256, 256, 0, stream>>>(g_bf, meanb, invb, fgn_g, fgn_b, fgn_a, hn_bf);

  // FFN2 (K=512, old kernel): x_out = hn @ ffW2 + ffb2 -> d_out, fused mean-pool
  zerof_kernel<<<NB*DDIM/256, 256, 0, stream>>>((float*)d_out + (size_t)NTOT*DDIM, NB*DDIM);
  GemmCfg c2 = {};
  for (int i2 = 0; i2 < 4; ++i2){ c2.B[i2] = ffW2; c2.bias[i2] = ffb2; c2.o32[i2] = (float*)d_out; }
  c2.ldb = DDIM; c2.ld_out = DDIM; c2.K = HFF; c2.bcolmul = 0; c2.ocolmul = 0; c2.gelu = 0;
  c2.pool = (float*)d_out + (size_t)NTOT*DDIM;
  gemm_old<<<dim3(NTOT/128, 1), 256, 0, stream>>>(hn_bf, c2);
}